// Round 5
// baseline (16886.356 us; speedup 1.0000x reference)
//
#include <hip/hip_runtime.h>

#define HDIM   2048
#define TUNEDC 10
#define BATCH  16
#define TSTEPS 1024
#define NINP   8
#define NOUTP  8
#define RPW    8                 // rows of Wm per workgroup
#define NWG    (HDIM / RPW)      // 256 workgroups
#define NTHR   256

#define DT_C   0.001f
#define TAU_C  0.01f
#define PREL_C 1.0f
#define BETA_C 1.5f

// workspace layout (floats): 16 split counters (128 B apart) at 0, vbuf at 1024
#define NCTR      16
#define CTRSTRIDE 32             // ints; 128 B between counters (distinct lines)
#define VBUF_OFF  1024
#define VBUF_SZ   (BATCH * HDIM) // 32768 floats per buffer, two buffers

// LDS layout (floats): weights live in VGPRs, only reduce scratch remains
#define SCR_STRIDE 140
#define LDS_YH     (128 * SCR_STRIDE)
#define LDS_TOTAL  (LDS_YH + 256)            // 18176 floats = 72704 B

#define AGENT __HIP_MEMORY_SCOPE_AGENT

extern "C" __global__ __launch_bounds__(NTHR, 1)
void rnn_main(const float* __restrict__ x, const float* __restrict__ h0,
              const float* __restrict__ Wih, const float* __restrict__ Wt,
              const float* __restrict__ Wf, const float* __restrict__ Wmask,
              const float* __restrict__ tau_d,
              float* __restrict__ h_out, float* __restrict__ r_out,
              int* ctr, float* vbuf)
{
    extern __shared__ float smem[];
    float* scr = smem;            // [128][SCR_STRIDE] transpose-reduction scratch
    float* yh  = smem + LDS_YH;   // [128][2] half-sums

    const int wg   = blockIdx.x;
    const int tid  = threadIdx.x;
    const int lane = tid & 63;
    const int w    = tid >> 6;    // wave 0..3
    const int bg   = w & 1;       // batch group: batches 8*bg .. 8*bg+7
    const int kh   = w >> 1;      // k half
    const int r0   = wg * RPW;
    // SYNC CONTRACT (rounds 1-4): publish MUST be an atomic RMW issued after
    // the release fence (plain-store publish showed stale-v reads).  Sharded
    // 16-counter barrier is the proven protocol.  Do not weaken either.
    int* myctr = ctr + (wg & (NCTR - 1)) * CTRSTRIDE;

    // ---- masked recurrent weight slice into REGISTERS (time-invariant) ----
    // NUMERICS CONTRACT: lane owns k = kh*1024 + jj*64 + lane, jj = 0..15,
    // one multiply mask*base per element, accumulated as sequential fmaf in
    // jj order — bitwise identical to the baseline kernel's sums.
    float wreg[RPW][16];
    #pragma unroll
    for (int rl = 0; rl < RPW; ++rl) {
        const int r = r0 + rl;
        const float* mrow = Wmask + (size_t)r * HDIM;
        #pragma unroll
        for (int jj = 0; jj < 16; ++jj) {
            int k = kh * 1024 + jj * 64 + lane;
            float base = (k < TUNEDC) ? Wt[r * TUNEDC + k]
                                      : Wf[r * (HDIM - TUNEDC) + (k - TUNEDC)];
            wreg[rl][jj] = mrow[k] * base;
        }
    }

    // ---- owner threads (128): state (h,r,tanh h) lives in registers ----
    const bool owner = (tid < BATCH * RPW);
    const int ob  = tid >> 3;          // batch
    const int orl = tid & 7;           // local row
    const int oro = r0 + orl;          // global row
    float h_s = 0.f, r_s = PREL_C, hT_s = 0.f, itau_s = 1.f;
    float wihr[NINP];
    if (owner) {
        h_s   = h0[ob * HDIM + oro];
        hT_s  = tanhf(h_s);
        itau_s = 1.0f / tau_d[oro];
        #pragma unroll
        for (int k2 = 0; k2 < NINP; ++k2) wihr[k2] = Wih[oro * NINP + k2];
        // publish v_0 into buffer 0 (agent store: write-through to MALL)
        __hip_atomic_store(&vbuf[ob * HDIM + oro], r_s * hT_s,
                           __ATOMIC_RELAXED, AGENT);
    }
    // drain this wave's v stores to MALL before counting ourselves in
    __builtin_amdgcn_fence(__ATOMIC_RELEASE, "workgroup");
    __syncthreads();
    if (tid == 0)
        __hip_atomic_fetch_add(myctr, 1, __ATOMIC_RELAXED, AGENT);

    for (int t = 0; t < TSTEPS; ++t) {
        // ---- sharded-counter barrier (proven protocol, round 4) ----
        if (w == 0) {
            const int target = NCTR * (t + 1);
            while (true) {
                int cv = 0x7fffffff;
                if (lane < NCTR)
                    cv = __hip_atomic_load(&ctr[lane * CTRSTRIDE],
                                           __ATOMIC_RELAXED, AGENT);
                if (__all(cv >= target)) break;
                __builtin_amdgcn_s_sleep(1);
            }
        }
        __syncthreads();
        // ---- CACHED-BROADCAST PROTOCOL (new this round): after the barrier,
        // buffer t&1 is stable for the whole step.  Each thread issues an
        // acquire-agent fence (s_waitcnt + buffer_inv: invalidates its CU's
        // L1 and the XCD's L2) and then reads v with PLAIN cacheable loads.
        // First readers per XCD fill L2 from MALL; the rest hit L2 — cuts
        // the 32 MB/step MALL broadcast ~8-30x.  Ordering: each wave's loads
        // follow its OWN inv (same-wave program order), so no cross-wave
        // visibility hole; data is globally in MALL per the publish contract.
        __builtin_amdgcn_fence(__ATOMIC_ACQUIRE, "agent");

        const float* vc = vbuf + (t & 1) * VBUF_SZ;

        // ---- y[8 rows][16 batches] = W_slice @ v ; weights from VGPRs,
        //      v via coalesced PLAIN 4 B loads (baseline lane->k map) ----
        float acc[RPW][8];
        #pragma unroll
        for (int rl = 0; rl < RPW; ++rl)
            #pragma unroll
            for (int bl = 0; bl < 8; ++bl) acc[rl][bl] = 0.f;

        #pragma unroll
        for (int jj = 0; jj < 16; ++jj) {
            const int k = kh * 1024 + jj * 64 + lane;  // lane-consecutive dwords
            float vv[8];
            #pragma unroll
            for (int bl = 0; bl < 8; ++bl)
                vv[bl] = vc[(8 * bg + bl) * HDIM + k];
            #pragma unroll
            for (int rl = 0; rl < RPW; ++rl) {
                float wv = wreg[rl][jj];
                #pragma unroll
                for (int bl = 0; bl < 8; ++bl)
                    acc[rl][bl] = fmaf(wv, vv[bl], acc[rl][bl]);
            }
        }

        // ---- transpose-reduce over the 128 k-splits via LDS (baseline order) ----
        {
            const int ks = kh * 64 + lane;
            #pragma unroll
            for (int rl = 0; rl < RPW; ++rl)
                #pragma unroll
                for (int bl = 0; bl < 8; ++bl) {
                    int p = (8 * bg + bl) * 8 + rl;     // pair = b*8 + rl
                    scr[p * SCR_STRIDE + ks] = acc[rl][bl];
                }
        }
        __syncthreads();
        {
            const int p  = tid & 127;
            const int hh = tid >> 7;
            const float4* s4 = (const float4*)(scr + p * SCR_STRIDE + hh * 64);
            float s = 0.f;
            #pragma unroll
            for (int i = 0; i < 16; ++i) {
                float4 q = s4[i];
                s += q.x + q.y + q.z + q.w;
            }
            yh[p * 2 + hh] = s;
        }
        __syncthreads();

        // ---- owner integrates state and publishes next v (baseline source) ----
        float hn = 0.f, rn = 0.f;
        if (owner) {
            float y = yh[tid * 2] + yh[tid * 2 + 1];
            const float* xt = x + ((size_t)ob * TSTEPS + t) * NINP;
            float xin = 0.f;
            #pragma unroll
            for (int k2 = 0; k2 < NINP; ++k2)
                xin = fmaf(xt[k2], wihr[k2], xin);
            // dh = (-h + rec + xin)/TAU ; h' = h + dh*DT   (W_zh term is exactly 0)
            float dh = (y + xin - h_s) * (1.0f / TAU_C);
            hn = fmaf(dh, DT_C, h_s);
            // r' = r + ((1-r)/tau_depr - 1.5*r*tanh(h))*DT  (uses previous tanh h)
            rn = r_s + ((PREL_C - r_s) * itau_s - BETA_C * r_s * hT_s) * DT_C;
            float hTn = tanhf(hn);
            h_s = hn; r_s = rn; hT_s = hTn;
            if (t + 1 < TSTEPS) {
                float* vn = vbuf + ((t + 1) & 1) * VBUF_SZ;
                __hip_atomic_store(&vn[ob * HDIM + oro], r_s * hT_s,
                                   __ATOMIC_RELAXED, AGENT);
            }
        }
        if (t + 1 < TSTEPS) {
            // drain THIS WG's v stores before counting ourselves in.
            __builtin_amdgcn_fence(__ATOMIC_RELEASE, "workgroup");
            __syncthreads();
            if (tid == 0)
                __hip_atomic_fetch_add(myctr, 1, __ATOMIC_RELAXED, AGENT);
        }
        // output stores AFTER the barrier add: off the critical drain path
        // (they drain in the background during the next barrier wait; the
        // next acquire fence's waitcnt sees them already acked)
        if (owner) {
            size_t oidx = ((size_t)ob * TSTEPS + t) * HDIM + oro;
            h_out[oidx] = hn;
            r_out[oidx] = rn;
        }
    }
}

// z[b,t,:] = tanh(h[b,t,:]) @ W_hz.T — decoupled post-pass, one block per (b,t)
extern "C" __global__ __launch_bounds__(256, 2)
void z_kernel(const float* __restrict__ h_out, const float* __restrict__ Whz,
              float* __restrict__ z_out)
{
    const int bt  = blockIdx.x;
    const int tid = threadIdx.x;
    const float4* hp = (const float4*)(h_out + (size_t)bt * HDIM);
    float4 a = hp[tid * 2], b4 = hp[tid * 2 + 1];
    float th[8] = { tanhf(a.x),  tanhf(a.y),  tanhf(a.z),  tanhf(a.w),
                    tanhf(b4.x), tanhf(b4.y), tanhf(b4.z), tanhf(b4.w) };
    float acc[NOUTP];
    #pragma unroll
    for (int o = 0; o < NOUTP; ++o) {
        const float4* wp = (const float4*)(Whz + o * HDIM);
        float4 wa = wp[tid * 2], wb = wp[tid * 2 + 1];
        acc[o] = th[0]*wa.x + th[1]*wa.y + th[2]*wa.z + th[3]*wa.w
               + th[4]*wb.x + th[5]*wb.y + th[6]*wb.z + th[7]*wb.w;
    }
    #pragma unroll
    for (int off = 32; off > 0; off >>= 1)
        #pragma unroll
        for (int o = 0; o < NOUTP; ++o)
            acc[o] += __shfl_down(acc[o], off, 64);
    __shared__ float part[4][NOUTP];
    if ((tid & 63) == 0)
        for (int o = 0; o < NOUTP; ++o) part[tid >> 6][o] = acc[o];
    __syncthreads();
    if (tid < NOUTP)
        z_out[(size_t)bt * NOUTP + tid] =
            part[0][tid] + part[1][tid] + part[2][tid] + part[3][tid];
}

extern "C" void kernel_launch(void* const* d_in, const int* in_sizes, int n_in,
                              void* d_out, int out_size, void* d_ws, size_t ws_size,
                              hipStream_t stream)
{
    (void)in_sizes; (void)n_in; (void)out_size; (void)ws_size;
    const float* x    = (const float*)d_in[0];
    const float* h0   = (const float*)d_in[1];
    const float* Wih  = (const float*)d_in[2];
    const float* Wt   = (const float*)d_in[3];
    const float* Wf   = (const float*)d_in[4];
    const float* Wm   = (const float*)d_in[5];
    const float* Whz  = (const float*)d_in[6];
    // d_in[7] = W_zh: all zeros (echo_state=False) -> its term is exactly 0, skipped.
    const float* taud = (const float*)d_in[8];

    float* z_out = (float*)d_out;
    float* h_out = z_out + (size_t)BATCH * TSTEPS * NOUTP;
    float* r_out = h_out + (size_t)BATCH * TSTEPS * HDIM;

    int*   ctr  = (int*)d_ws;
    float* vbuf = (float*)d_ws + VBUF_OFF;

    hipFuncSetAttribute((const void*)rnn_main,
                        hipFuncAttributeMaxDynamicSharedMemorySize,
                        LDS_TOTAL * (int)sizeof(float));

    // zero the whole pre-vbuf region (all 16 counters)
    hipMemsetAsync(ctr, 0, VBUF_OFF * sizeof(int), stream);
    rnn_main<<<NWG, NTHR, LDS_TOTAL * sizeof(float), stream>>>(
        x, h0, Wih, Wt, Wf, Wm, taud, h_out, r_out, ctr, vbuf);
    z_kernel<<<BATCH * TSTEPS, 256, 0, stream>>>(h_out, Whz, z_out);
}

// Round 6
// 7586.124 us; speedup vs baseline: 2.2260x; 2.2260x over previous
//
#include <hip/hip_runtime.h>

#define HDIM   2048
#define TUNEDC 10
#define BATCH  16
#define TSTEPS 1024
#define NINP   8
#define NOUTP  8
#define RPW    16                // rows of Wm per workgroup
#define NWG    (HDIM / RPW)      // 128 workgroups
#define NTHR   512               // 8 waves

#define DT_C   0.001f
#define TAU_C  0.01f
#define PREL_C 1.0f
#define BETA_C 1.5f

// workspace layout (floats): 16 split counters (128 B apart) at 0, vbuf at 1024
#define NCTR      16
#define CTRSTRIDE 32             // ints; 128 B between counters (distinct lines)
#define VBUF_OFF  1024
#define VBUF_SZ   (BATCH * HDIM) // 32768 floats per buffer, two buffers

// LDS layout (floats)
#define LDS_V      0                          // [2][2048] double-buffered v chunk
#define SCR_STRIDE 132
#define LDS_SCR    4096                       // [256][SCR_STRIDE]
#define LDS_YH     (LDS_SCR + 256 * SCR_STRIDE)
#define LDS_TOTAL  (LDS_YH + 512)             // 38400 floats = 153600 B

#define AGENT __HIP_MEMORY_SCOPE_AGENT

typedef unsigned long long ull;

extern "C" __global__ __launch_bounds__(NTHR, 2)
void rnn_main(const float* __restrict__ x, const float* __restrict__ h0,
              const float* __restrict__ Wih, const float* __restrict__ Wt,
              const float* __restrict__ Wf, const float* __restrict__ Wmask,
              const float* __restrict__ tau_d,
              float* __restrict__ h_out, float* __restrict__ r_out,
              int* ctr, float* vbuf)
{
    extern __shared__ float smem[];
    float* ldsv = smem + LDS_V;    // staged v chunks, [buf][b*128 + kh*64 + u]
    float* scr  = smem + LDS_SCR;  // transpose-reduction scratch
    float* yh   = smem + LDS_YH;   // [256][2] half-sums

    const int wg   = blockIdx.x;
    const int tid  = threadIdx.x;
    const int lane = tid & 63;
    const int w    = tid >> 6;     // wave 0..7
    const int bg   = w & 1;        // batch group: batches 8*bg .. 8*bg+7
    const int kh   = (w >> 1) & 1; // k half
    const int rh   = w >> 2;       // row half: rows rh*8 .. rh*8+7 of this WG
    const int r0   = wg * RPW;
    // SYNC CONTRACT (rounds 1-5): publish = atomic RMW after release fence
    // (plain-store publish -> stale reads).  NEVER put an agent-acquire
    // fence in the step loop (round 5: buffer_inv storm + vmcnt(0) drain of
    // output stores = 2.5x regression).  sc1 relaxed loads + sharded-counter
    // RMW barrier is the proven protocol.
    int* myctr = ctr + (wg & (NCTR - 1)) * CTRSTRIDE;

    // staging decomposition: thread stages 4 consecutive floats of the 2048-
    // float chunk (all 16 batches x both k-halves for one jj).
    const int sflat = tid * 4;            // 0..2044
    const int sb    = sflat >> 7;         // batch 0..15
    const int skh   = (sflat >> 6) & 1;   // k half
    const int su    = sflat & 63;         // 0,4,..,60 within the 64-float run

    // ---- masked recurrent weight slice into REGISTERS (time-invariant) ----
    // NUMERICS CONTRACT: lane owns k = kh*1024 + jj*64 + lane, jj = 0..15,
    // one multiply mask*base per element, accumulated as sequential fmaf in
    // jj order — bitwise identical to the baseline kernel's sums.
    float wreg[8][16];
    #pragma unroll
    for (int rl = 0; rl < 8; ++rl) {
        const int r = r0 + rh * 8 + rl;
        const float* mrow = Wmask + (size_t)r * HDIM;
        #pragma unroll
        for (int jj = 0; jj < 16; ++jj) {
            int k = kh * 1024 + jj * 64 + lane;
            float base = (k < TUNEDC) ? Wt[r * TUNEDC + k]
                                      : Wf[r * (HDIM - TUNEDC) + (k - TUNEDC)];
            wreg[rl][jj] = mrow[k] * base;
        }
    }

    // ---- owner threads (256): tid = ob*16 + orl == scr pair index ----
    const bool owner = (tid < BATCH * RPW);
    const int ob  = tid >> 4;          // batch
    const int orl = tid & 15;          // local row
    const int oro = r0 + orl;          // global row
    float h_s = 0.f, r_s = PREL_C, hT_s = 0.f, itau_s = 1.f;
    float wihr[NINP];
    if (owner) {
        h_s   = h0[ob * HDIM + oro];
        hT_s  = tanhf(h_s);
        itau_s = 1.0f / tau_d[oro];
        #pragma unroll
        for (int k2 = 0; k2 < NINP; ++k2) wihr[k2] = Wih[oro * NINP + k2];
        __hip_atomic_store(&vbuf[ob * HDIM + oro], r_s * hT_s,
                           __ATOMIC_RELAXED, AGENT);
    }
    __builtin_amdgcn_fence(__ATOMIC_RELEASE, "workgroup");
    __syncthreads();
    if (tid == 0)
        __hip_atomic_fetch_add(myctr, 1, __ATOMIC_RELAXED, AGENT);

    for (int t = 0; t < TSTEPS; ++t) {
        // ---- sharded-counter barrier: each counter gets NWG/NCTR=8 adds ----
        if (w == 0) {
            const int target = (NWG / NCTR) * (t + 1);
            while (true) {
                int cv = 0x7fffffff;
                if (lane < NCTR)
                    cv = __hip_atomic_load(&ctr[lane * CTRSTRIDE],
                                           __ATOMIC_RELAXED, AGENT);
                if (__all(cv >= target)) break;
                __builtin_amdgcn_s_sleep(1);
            }
        }
        __syncthreads();

        const float* vc = vbuf + (t & 1) * VBUF_SZ;
        const float* sbase = vc + sb * HDIM + skh * 1024 + su;

        // ---- prologue: stage chunks 0 and 1 (2 jj deep) ----
        ull ca = __hip_atomic_load((const ull*)(sbase), __ATOMIC_RELAXED, AGENT);
        ull cb = __hip_atomic_load((const ull*)(sbase) + 1, __ATOMIC_RELAXED, AGENT);
        ull na = __hip_atomic_load((const ull*)(sbase + 64), __ATOMIC_RELAXED, AGENT);
        ull nb = __hip_atomic_load((const ull*)(sbase + 64) + 1, __ATOMIC_RELAXED, AGENT);
        {
            union { ull u; float f[2]; } p0, p1; p0.u = ca; p1.u = cb;
            float4 q = { p0.f[0], p0.f[1], p1.f[0], p1.f[1] };
            *(float4*)&ldsv[sflat] = q;           // chunk 0 -> buf 0
        }
        __syncthreads();                          // chunk 0 visible

        float acc[8][8];
        #pragma unroll
        for (int rl = 0; rl < 8; ++rl)
            #pragma unroll
            for (int bl = 0; bl < 8; ++bl) acc[rl][bl] = 0.f;

        // ---- jj pipeline: compute(jj) from buf[jj&1]; stage jj+1 into the
        // other buffer (regs loaded last iter); issue loads for jj+2.
        // Fully unrolled -> all buffer/reg indices static (no scratch).
        #pragma unroll
        for (int jj = 0; jj < 16; ++jj) {
            const int cur = jj & 1;
            ull fa = 0, fb = 0;
            if (jj + 2 < 16) {   // issue loads for chunk jj+2 (in flight across compute)
                fa = __hip_atomic_load((const ull*)(sbase + (jj + 2) * 64),
                                       __ATOMIC_RELAXED, AGENT);
                fb = __hip_atomic_load((const ull*)(sbase + (jj + 2) * 64) + 1,
                                       __ATOMIC_RELAXED, AGENT);
            }
            // compute(jj): vv from LDS (stride-1, conflict-free)
            float vv[8];
            #pragma unroll
            for (int bl = 0; bl < 8; ++bl)
                vv[bl] = ldsv[cur * 2048 + (8 * bg + bl) * 128 + kh * 64 + lane];
            #pragma unroll
            for (int rl = 0; rl < 8; ++rl) {
                float wv = wreg[rl][jj];
                #pragma unroll
                for (int bl = 0; bl < 8; ++bl)
                    acc[rl][bl] = fmaf(wv, vv[bl], acc[rl][bl]);
            }
            if (jj + 1 < 16) {   // stage chunk jj+1 into the other buffer
                union { ull u; float f[2]; } p0, p1; p0.u = na; p1.u = nb;
                float4 q = { p0.f[0], p0.f[1], p1.f[0], p1.f[1] };
                *(float4*)&ldsv[(cur ^ 1) * 2048 + sflat] = q;
            }
            na = fa; nb = fb;
            if (jj + 1 < 16) __syncthreads();     // chunk jj+1 ready
        }

        // ---- transpose-reduce over the 128 k-splits via LDS (same tree) ----
        {
            const int ks = kh * 64 + lane;
            #pragma unroll
            for (int rl = 0; rl < 8; ++rl)
                #pragma unroll
                for (int bl = 0; bl < 8; ++bl) {
                    int p = (8 * bg + bl) * 16 + rh * 8 + rl;  // pair = b*16+row
                    scr[p * SCR_STRIDE + ks] = acc[rl][bl];
                }
        }
        __syncthreads();
        {
            const int p  = tid & 255;
            const int hh = tid >> 8;
            const float4* s4 = (const float4*)(scr + p * SCR_STRIDE + hh * 64);
            float s = 0.f;
            #pragma unroll
            for (int i = 0; i < 16; ++i) {
                float4 q = s4[i];
                s += q.x + q.y + q.z + q.w;
            }
            yh[p * 2 + hh] = s;
        }
        __syncthreads();

        // ---- owner integrates state and publishes next v (baseline source) ----
        float hn = 0.f, rn = 0.f;
        if (owner) {
            float y = yh[tid * 2] + yh[tid * 2 + 1];   // pair index == tid
            const float* xt = x + ((size_t)ob * TSTEPS + t) * NINP;
            float xin = 0.f;
            #pragma unroll
            for (int k2 = 0; k2 < NINP; ++k2)
                xin = fmaf(xt[k2], wihr[k2], xin);
            // dh = (-h + rec + xin)/TAU ; h' = h + dh*DT   (W_zh term is exactly 0)
            float dh = (y + xin - h_s) * (1.0f / TAU_C);
            hn = fmaf(dh, DT_C, h_s);
            // r' = r + ((1-r)/tau_depr - 1.5*r*tanh(h))*DT  (uses previous tanh h)
            rn = r_s + ((PREL_C - r_s) * itau_s - BETA_C * r_s * hT_s) * DT_C;
            float hTn = tanhf(hn);
            h_s = hn; r_s = rn; hT_s = hTn;
            if (t + 1 < TSTEPS) {
                float* vn = vbuf + ((t + 1) & 1) * VBUF_SZ;
                __hip_atomic_store(&vn[ob * HDIM + oro], r_s * hT_s,
                                   __ATOMIC_RELAXED, AGENT);
            }
        }
        if (t + 1 < TSTEPS) {
            __builtin_amdgcn_fence(__ATOMIC_RELEASE, "workgroup");
            __syncthreads();
            if (tid == 0)
                __hip_atomic_fetch_add(myctr, 1, __ATOMIC_RELAXED, AGENT);
        }
        // output stores AFTER the barrier add: off the critical drain path
        if (owner) {
            size_t oidx = ((size_t)ob * TSTEPS + t) * HDIM + oro;
            h_out[oidx] = hn;
            r_out[oidx] = rn;
        }
    }
}

// z[b,t,:] = tanh(h[b,t,:]) @ W_hz.T — decoupled post-pass, one block per (b,t)
extern "C" __global__ __launch_bounds__(256, 2)
void z_kernel(const float* __restrict__ h_out, const float* __restrict__ Whz,
              float* __restrict__ z_out)
{
    const int bt  = blockIdx.x;
    const int tid = threadIdx.x;
    const float4* hp = (const float4*)(h_out + (size_t)bt * HDIM);
    float4 a = hp[tid * 2], b4 = hp[tid * 2 + 1];
    float th[8] = { tanhf(a.x),  tanhf(a.y),  tanhf(a.z),  tanhf(a.w),
                    tanhf(b4.x), tanhf(b4.y), tanhf(b4.z), tanhf(b4.w) };
    float acc[NOUTP];
    #pragma unroll
    for (int o = 0; o < NOUTP; ++o) {
        const float4* wp = (const float4*)(Whz + o * HDIM);
        float4 wa = wp[tid * 2], wb = wp[tid * 2 + 1];
        acc[o] = th[0]*wa.x + th[1]*wa.y + th[2]*wa.z + th[3]*wa.w
               + th[4]*wb.x + th[5]*wb.y + th[6]*wb.z + th[7]*wb.w;
    }
    #pragma unroll
    for (int off = 32; off > 0; off >>= 1)
        #pragma unroll
        for (int o = 0; o < NOUTP; ++o)
            acc[o] += __shfl_down(acc[o], off, 64);
    __shared__ float part[4][NOUTP];
    if ((tid & 63) == 0)
        for (int o = 0; o < NOUTP; ++o) part[tid >> 6][o] = acc[o];
    __syncthreads();
    if (tid < NOUTP)
        z_out[(size_t)bt * NOUTP + tid] =
            part[0][tid] + part[1][tid] + part[2][tid] + part[3][tid];
}

extern "C" void kernel_launch(void* const* d_in, const int* in_sizes, int n_in,
                              void* d_out, int out_size, void* d_ws, size_t ws_size,
                              hipStream_t stream)
{
    (void)in_sizes; (void)n_in; (void)out_size; (void)ws_size;
    const float* x    = (const float*)d_in[0];
    const float* h0   = (const float*)d_in[1];
    const float* Wih  = (const float*)d_in[2];
    const float* Wt   = (const float*)d_in[3];
    const float* Wf   = (const float*)d_in[4];
    const float* Wm   = (const float*)d_in[5];
    const float* Whz  = (const float*)d_in[6];
    // d_in[7] = W_zh: all zeros (echo_state=False) -> its term is exactly 0, skipped.
    const float* taud = (const float*)d_in[8];

    float* z_out = (float*)d_out;
    float* h_out = z_out + (size_t)BATCH * TSTEPS * NOUTP;
    float* r_out = h_out + (size_t)BATCH * TSTEPS * HDIM;

    int*   ctr  = (int*)d_ws;
    float* vbuf = (float*)d_ws + VBUF_OFF;

    hipFuncSetAttribute((const void*)rnn_main,
                        hipFuncAttributeMaxDynamicSharedMemorySize,
                        LDS_TOTAL * (int)sizeof(float));

    // zero the whole pre-vbuf region (all 16 counters)
    hipMemsetAsync(ctr, 0, VBUF_OFF * sizeof(int), stream);
    rnn_main<<<NWG, NTHR, LDS_TOTAL * sizeof(float), stream>>>(
        x, h0, Wih, Wt, Wf, Wm, taud, h_out, r_out, ctr, vbuf);
    z_kernel<<<BATCH * TSTEPS, 256, 0, stream>>>(h_out, Whz, z_out);
}